// Round 3
// baseline (1247.834 us; speedup 1.0000x reference)
//
#include <hip/hip_runtime.h>
#include <math.h>

#define CH 512
#define NTOK 1024

typedef short          bf16x8 __attribute__((ext_vector_type(8)));
typedef unsigned short u16x8  __attribute__((ext_vector_type(8)));
typedef float          f32x4  __attribute__((ext_vector_type(4)));

__device__ __forceinline__ float bf2f(unsigned short u) {
    unsigned int x = ((unsigned int)u) << 16;
    return __builtin_bit_cast(float, x);
}
__device__ __forceinline__ unsigned short f2bf(float f) {
    unsigned int x = __builtin_bit_cast(unsigned int, f);
    x += 0x7fff + ((x >> 16) & 1);   // RNE
    return (unsigned short)(x >> 16);
}

// Scalar dual-dtype load: isf ? fp32 : bf16
__device__ __forceinline__ float loads(const void* p, size_t idx, int isf) {
    return isf ? ((const float*)p)[idx] : bf2f(((const unsigned short*)p)[idx]);
}
// 8 contiguous elements -> float[8]; idx must be a multiple of 4.
__device__ __forceinline__ void load8f(const void* p, size_t idx, int isf, float* v) {
    if (isf) {
        const f32x4* q = (const f32x4*)((const float*)p + idx);
        f32x4 a = q[0], b = q[1];
        v[0]=a[0]; v[1]=a[1]; v[2]=a[2]; v[3]=a[3];
        v[4]=b[0]; v[5]=b[1]; v[6]=b[2]; v[7]=b[3];
    } else {
        u16x8 u = *(const u16x8*)((const unsigned short*)p + idx);
        #pragma unroll
        for (int j = 0; j < 8; ++j) v[j] = bf2f(u[j]);
    }
}

// ---------------- dtype probe: exponent fields of raw halves ----------------
// bf16 N(0,1) data: exp field <= 0x81 always. fp32 data read as uint16 halves:
// even halves are uniform random bits -> ~25% have exp >= 0xC0. One block.
__global__ __launch_bounds__(256) void probe_kernel(
    const unsigned short* __restrict__ x, int* __restrict__ flag)
{
    __shared__ int sh[256];
    int t = threadIdx.x, cnt = 0;
    for (int i = t; i < 8192; i += 256) {
        int e = (x[i] >> 7) & 0xFF;
        cnt += (e >= 0xC0) ? 1 : 0;
    }
    sh[t] = cnt;
    __syncthreads();
    for (int s = 128; s > 0; s >>= 1) {
        if (t < s) sh[t] += sh[t + s];
        __syncthreads();
    }
    if (t == 0) *flag = (sh[0] > 0) ? 1 : 0;
}

// ---------------- GroupNorm stats: one block per (b, group) ----------------
__global__ __launch_bounds__(256) void stats_kernel(
    const void* __restrict__ x, float* __restrict__ stats,
    const int* __restrict__ flag)
{
    int isf = *flag;
    int bg = blockIdx.x;                      // b*32 + g; 16384 contiguous elems
    size_t base = (size_t)bg * 16384;
    int t = threadIdx.x;

    float s = 0.f, sq = 0.f;
    for (int i = t; i < 2048; i += 256) {
        float v[8];
        load8f(x, base + (size_t)i * 8, isf, v);
        #pragma unroll
        for (int j = 0; j < 8; ++j) { s += v[j]; sq += v[j] * v[j]; }
    }
    for (int off = 32; off > 0; off >>= 1) {
        s  += __shfl_down(s, off);
        sq += __shfl_down(sq, off);
    }
    __shared__ float red[8];
    int lane = t & 63, wv = t >> 6;
    if (lane == 0) { red[wv] = s; red[wv + 4] = sq; }
    __syncthreads();
    if (t == 0) {
        float ts = red[0] + red[1] + red[2] + red[3];
        float tq = red[4] + red[5] + red[6] + red[7];
        float mean = ts * (1.f / 16384.f);
        float var  = tq * (1.f / 16384.f) - mean * mean;
        stats[bg * 2]     = mean;
        stats[bg * 2 + 1] = rsqrtf(fmaxf(var, 0.f) + 1e-6f);
    }
}

// ------------- GEMM: out[b][o][n] = sum_c W[o][c]*Xn[b][c][n] + bias[o] (+resid) -------
// X/W/bias/resid are dual-dtype (per flag). Internal LDS + MFMA in bf16.
// apply_flag: 1 -> store per flag dtype (final output); 0 -> store bf16 (ws buffer).
__global__ __launch_bounds__(256) void gemm_kernel(
    const void* __restrict__ W,      // M x 512
    const void* __restrict__ bias,   // M
    const void* X,                   // b-strided by xstride (dual dtype if stats)
    long long xstride,
    void* out,                       // b-strided by ostride
    long long ostride,
    const void* __restrict__ resid,  // null or (b,512,1024) dual dtype
    int M,
    const float* __restrict__ stats, // null -> no GN (and X is bf16 ws buffer)
    const void* __restrict__ gw,
    const void* __restrict__ gb,
    const int* __restrict__ flag,
    int apply_flag)
{
    int isf = *flag;
    int x_isf = (stats != nullptr) ? isf : 0;   // ws buffers are always bf16
    __shared__ unsigned short Xsh[64 * 40];     // [n][k], pad 40
    int n0 = blockIdx.x * 64;
    int m0 = blockIdx.y * 64;
    int b  = blockIdx.z;
    int t = threadIdx.x;
    int lane = t & 63, wv = t >> 6;
    int qd = lane >> 4;       // k-chunk 0..3
    int lm = lane & 15;       // A row / B col within 16

    size_t xbase = (size_t)b * xstride;
    size_t woff  = (size_t)(m0 + wv * 16 + lm) * CH + qd * 8;

    int kloc = t >> 3;        // staging k 0..31
    int n8 = (t & 7) * 8;     // staging n {0,8,...,56}

    f32x4 acc[4] = {{0.f,0.f,0.f,0.f},{0.f,0.f,0.f,0.f},
                    {0.f,0.f,0.f,0.f},{0.f,0.f,0.f,0.f}};

    for (int kk = 0; kk < CH; kk += 32) {
        __syncthreads();
        int c = kk + kloc;
        float v[8];
        load8f(X, xbase + (size_t)c * NTOK + n0 + n8, x_isf, v);
        if (stats) {
            const float* st = stats + ((size_t)b * 32 + (c >> 4)) * 2;
            float mean = st[0], rstd = st[1];
            float gam = loads(gw, c, isf), bet = loads(gb, c, isf);
            #pragma unroll
            for (int j = 0; j < 8; ++j)
                Xsh[(n8 + j) * 40 + kloc] = f2bf((v[j] - mean) * rstd * gam + bet);
        } else {
            #pragma unroll
            for (int j = 0; j < 8; ++j)
                Xsh[(n8 + j) * 40 + kloc] = f2bf(v[j]);
        }
        __syncthreads();

        bf16x8 a;
        if (isf) {
            float wv8[8];
            load8f(W, woff + kk, 1, wv8);
            #pragma unroll
            for (int j = 0; j < 8; ++j) a[j] = (short)f2bf(wv8[j]);
        } else {
            a = *(const bf16x8*)((const unsigned short*)W + woff + kk);
        }
        #pragma unroll
        for (int ns = 0; ns < 4; ++ns) {
            bf16x8 bb = *(const bf16x8*)&Xsh[(ns * 16 + lm) * 40 + qd * 8];
            acc[ns] = __builtin_amdgcn_mfma_f32_16x16x32_bf16(a, bb, acc[ns], 0, 0, 0);
        }
    }

    #pragma unroll
    for (int ns = 0; ns < 4; ++ns) {
        #pragma unroll
        for (int r = 0; r < 4; ++r) {
            int o = m0 + wv * 16 + qd * 4 + r;        // D row = (lane>>4)*4 + r
            int n = n0 + ns * 16 + lm;                // D col = lane&15
            float vv = acc[ns][r] + loads(bias, o, isf);
            if (resid) vv += loads(resid, ((size_t)b * CH + o) * NTOK + n, isf);
            size_t oidx = (size_t)b * ostride + (size_t)o * NTOK + n;
            if (apply_flag && isf) ((float*)out)[oidx] = vv;
            else ((unsigned short*)out)[oidx] = f2bf(vv);
        }
    }
}

// ------------- Attention: 1 thread = 1 query, flash-style online softmax -------------
// qkv (ws, always bf16): rows [0,512) q, [512,1024) k, [1024,1536) v per batch.
// Output written in-place into the q region (block reads its own q cols first).
__global__ __launch_bounds__(256) void attn_kernel(
    const unsigned short* qkv, unsigned short* outq)
{
    __shared__ float Ksh[64 * 36];
    __shared__ float Vsh[64 * 36];
    int q0 = blockIdx.x * 256;
    int h = blockIdx.y;
    int b = blockIdx.z;
    int t = threadIdx.x;
    int n = q0 + t;

    const unsigned short* qb = qkv + ((size_t)b * 1536 + h * 64) * NTOK;
    const unsigned short* kb = qkv + ((size_t)b * 1536 + 512 + h * 64) * NTOK;
    const unsigned short* vb = qkv + ((size_t)b * 1536 + 1024 + h * 64) * NTOK;

    float q[64], O[64];
    #pragma unroll
    for (int c = 0; c < 64; ++c) {
        q[c] = bf2f(qb[(size_t)c * NTOK + n]) * 0.125f;
        O[c] = 0.f;
    }
    float mrun = -1e30f, lrun = 0.f;

    int sc = t >> 2;            // staging channel 0..63
    int m8 = (t & 3) * 8;       // staging m {0,8,16,24}

    for (int m0 = 0; m0 < NTOK; m0 += 32) {
        __syncthreads();
        {
            u16x8 ku = *(const u16x8*)(kb + (size_t)sc * NTOK + m0 + m8);
            u16x8 vu = *(const u16x8*)(vb + (size_t)sc * NTOK + m0 + m8);
            f32x4 k0 = {bf2f(ku[0]), bf2f(ku[1]), bf2f(ku[2]), bf2f(ku[3])};
            f32x4 k1 = {bf2f(ku[4]), bf2f(ku[5]), bf2f(ku[6]), bf2f(ku[7])};
            f32x4 v0 = {bf2f(vu[0]), bf2f(vu[1]), bf2f(vu[2]), bf2f(vu[3])};
            f32x4 v1 = {bf2f(vu[4]), bf2f(vu[5]), bf2f(vu[6]), bf2f(vu[7])};
            *(f32x4*)&Ksh[sc * 36 + m8]     = k0;
            *(f32x4*)&Ksh[sc * 36 + m8 + 4] = k1;
            *(f32x4*)&Vsh[sc * 36 + m8]     = v0;
            *(f32x4*)&Vsh[sc * 36 + m8 + 4] = v1;
        }
        __syncthreads();

        f32x4 s4[8];
        #pragma unroll
        for (int j = 0; j < 8; ++j) s4[j] = (f32x4){0.f, 0.f, 0.f, 0.f};
        #pragma unroll
        for (int c = 0; c < 64; ++c) {
            float qc = q[c];
            const f32x4* kr = (const f32x4*)&Ksh[c * 36];
            #pragma unroll
            for (int j = 0; j < 8; ++j)
                s4[j] += qc * kr[j];
        }

        float tmax = s4[0][0];
        #pragma unroll
        for (int j = 0; j < 8; ++j)
            #pragma unroll
            for (int i = 0; i < 4; ++i) tmax = fmaxf(tmax, s4[j][i]);
        float newm = fmaxf(mrun, tmax);
        float alpha = __expf(mrun - newm);
        float psum = 0.f;
        #pragma unroll
        for (int j = 0; j < 8; ++j)
            #pragma unroll
            for (int i = 0; i < 4; ++i) {
                float p = __expf(s4[j][i] - newm);
                s4[j][i] = p;
                psum += p;
            }
        lrun = lrun * alpha + psum;
        mrun = newm;

        #pragma unroll
        for (int c = 0; c < 64; ++c) {
            const f32x4* vr = (const f32x4*)&Vsh[c * 36];
            f32x4 a = (f32x4){0.f, 0.f, 0.f, 0.f};
            #pragma unroll
            for (int j = 0; j < 8; ++j)
                a += s4[j] * vr[j];
            O[c] = O[c] * alpha + (a[0] + a[1] + a[2] + a[3]);
        }
    }

    float inv = 1.f / lrun;
    unsigned short* ob = outq + ((size_t)b * 1536 + h * 64) * NTOK;
    #pragma unroll
    for (int c = 0; c < 64; ++c)
        ob[(size_t)c * NTOK + n] = f2bf(O[c] * inv);
}

extern "C" void kernel_launch(void* const* d_in, const int* in_sizes, int n_in,
                              void* d_out, int out_size, void* d_ws, size_t ws_size,
                              hipStream_t stream) {
    const void* x      = d_in[0];
    const void* norm_w = d_in[1];
    const void* norm_b = d_in[2];
    const void* qkv_w  = d_in[3];
    const void* qkv_b  = d_in[4];
    const void* proj_w = d_in[5];
    const void* proj_b = d_in[6];

    // ws: qkvb (8,1536,1024) bf16 = 24 MB | stats 256*2 f32 = 2 KB | flag 4 B
    const size_t QKV_BYTES = (size_t)8 * 1536 * 1024 * 2;
    if (ws_size < QKV_BYTES + 8192) return;
    unsigned short* qkvb = (unsigned short*)d_ws;
    float* stats = (float*)((char*)d_ws + QKV_BYTES);
    int* flag = (int*)((char*)d_ws + QKV_BYTES + 4096);

    probe_kernel<<<dim3(1), dim3(256), 0, stream>>>((const unsigned short*)x, flag);
    stats_kernel<<<dim3(256), dim3(256), 0, stream>>>(x, stats, flag);
    gemm_kernel<<<dim3(16, 24, 8), dim3(256), 0, stream>>>(
        qkv_w, qkv_b, x, (long long)CH * NTOK, qkvb, (long long)1536 * NTOK,
        nullptr, 1536, stats, norm_w, norm_b, flag, 0);
    attn_kernel<<<dim3(4, 8, 8), dim3(256), 0, stream>>>(qkvb, qkvb);
    gemm_kernel<<<dim3(16, 8, 8), dim3(256), 0, stream>>>(
        proj_w, proj_b, qkvb, (long long)1536 * NTOK, d_out, (long long)CH * NTOK,
        x, 512, nullptr, nullptr, nullptr, flag, 1);
}

// Round 4
// 258.045 us; speedup vs baseline: 4.8357x; 4.8357x over previous
//
#include <hip/hip_runtime.h>
#include <math.h>

#define CH 512
#define NTOK 1024

typedef short          bf16x8 __attribute__((ext_vector_type(8)));
typedef unsigned short u16x8  __attribute__((ext_vector_type(8)));
typedef unsigned short u16x4  __attribute__((ext_vector_type(4)));
typedef float          f32x4  __attribute__((ext_vector_type(4)));

__device__ __forceinline__ float bf2f(unsigned short u) {
    unsigned int x = ((unsigned int)u) << 16;
    return __builtin_bit_cast(float, x);
}
__device__ __forceinline__ unsigned short f2bf(float f) {
    unsigned int x = __builtin_bit_cast(unsigned int, f);
    x += 0x7fff + ((x >> 16) & 1);   // RNE
    return (unsigned short)(x >> 16);
}
__device__ __forceinline__ float loads(const void* p, size_t idx, int isf) {
    return isf ? ((const float*)p)[idx] : bf2f(((const unsigned short*)p)[idx]);
}
__device__ __forceinline__ void load8f(const void* p, size_t idx, int isf, float* v) {
    if (isf) {
        const f32x4* q = (const f32x4*)((const float*)p + idx);
        f32x4 a = q[0], b = q[1];
        v[0]=a[0]; v[1]=a[1]; v[2]=a[2]; v[3]=a[3];
        v[4]=b[0]; v[5]=b[1]; v[6]=b[2]; v[7]=b[3];
    } else {
        u16x8 u = *(const u16x8*)((const unsigned short*)p + idx);
        #pragma unroll
        for (int j = 0; j < 8; ++j) v[j] = bf2f(u[j]);
    }
}

// ---------------- dtype probe ----------------
__global__ __launch_bounds__(256) void probe_kernel(
    const unsigned short* __restrict__ x, int* __restrict__ flag)
{
    __shared__ int sh[256];
    int t = threadIdx.x, cnt = 0;
    for (int i = t; i < 8192; i += 256) {
        int e = (x[i] >> 7) & 0xFF;
        cnt += (e >= 0xC0) ? 1 : 0;
    }
    sh[t] = cnt;
    __syncthreads();
    for (int s = 128; s > 0; s >>= 1) {
        if (t < s) sh[t] += sh[t + s];
        __syncthreads();
    }
    if (t == 0) *flag = (sh[0] > 0) ? 1 : 0;
}

// ---------------- GroupNorm stats ----------------
__global__ __launch_bounds__(256) void stats_kernel(
    const void* __restrict__ x, float* __restrict__ stats,
    const int* __restrict__ flag)
{
    int isf = *flag;
    int bg = blockIdx.x;
    size_t base = (size_t)bg * 16384;
    int t = threadIdx.x;

    float s = 0.f, sq = 0.f;
    for (int i = t; i < 2048; i += 256) {
        float v[8];
        load8f(x, base + (size_t)i * 8, isf, v);
        #pragma unroll
        for (int j = 0; j < 8; ++j) { s += v[j]; sq += v[j] * v[j]; }
    }
    for (int off = 32; off > 0; off >>= 1) {
        s  += __shfl_down(s, off);
        sq += __shfl_down(sq, off);
    }
    __shared__ float red[8];
    int lane = t & 63, wv = t >> 6;
    if (lane == 0) { red[wv] = s; red[wv + 4] = sq; }
    __syncthreads();
    if (t == 0) {
        float ts = red[0] + red[1] + red[2] + red[3];
        float tq = red[4] + red[5] + red[6] + red[7];
        float mean = ts * (1.f / 16384.f);
        float var  = tq * (1.f / 16384.f) - mean * mean;
        stats[bg * 2]     = mean;
        stats[bg * 2 + 1] = rsqrtf(fmaxf(var, 0.f) + 1e-6f);
    }
}

// ------------- GEMM (unchanged from round 3, known-good) -------------
__global__ __launch_bounds__(256) void gemm_kernel(
    const void* __restrict__ W, const void* __restrict__ bias,
    const void* X, long long xstride,
    void* out, long long ostride,
    const void* __restrict__ resid, int M,
    const float* __restrict__ stats,
    const void* __restrict__ gw, const void* __restrict__ gb,
    const int* __restrict__ flag, int apply_flag)
{
    int isf = *flag;
    int x_isf = (stats != nullptr) ? isf : 0;
    __shared__ unsigned short Xsh[64 * 40];
    int n0 = blockIdx.x * 64;
    int m0 = blockIdx.y * 64;
    int b  = blockIdx.z;
    int t = threadIdx.x;
    int lane = t & 63, wv = t >> 6;
    int qd = lane >> 4;
    int lm = lane & 15;

    size_t xbase = (size_t)b * xstride;
    size_t woff  = (size_t)(m0 + wv * 16 + lm) * CH + qd * 8;

    int kloc = t >> 3;
    int n8 = (t & 7) * 8;

    f32x4 acc[4] = {{0.f,0.f,0.f,0.f},{0.f,0.f,0.f,0.f},
                    {0.f,0.f,0.f,0.f},{0.f,0.f,0.f,0.f}};

    for (int kk = 0; kk < CH; kk += 32) {
        __syncthreads();
        int c = kk + kloc;
        float v[8];
        load8f(X, xbase + (size_t)c * NTOK + n0 + n8, x_isf, v);
        if (stats) {
            const float* st = stats + ((size_t)b * 32 + (c >> 4)) * 2;
            float mean = st[0], rstd = st[1];
            float gam = loads(gw, c, isf), bet = loads(gb, c, isf);
            #pragma unroll
            for (int j = 0; j < 8; ++j)
                Xsh[(n8 + j) * 40 + kloc] = f2bf((v[j] - mean) * rstd * gam + bet);
        } else {
            #pragma unroll
            for (int j = 0; j < 8; ++j)
                Xsh[(n8 + j) * 40 + kloc] = f2bf(v[j]);
        }
        __syncthreads();

        bf16x8 a;
        if (isf) {
            float wv8[8];
            load8f(W, woff + kk, 1, wv8);
            #pragma unroll
            for (int j = 0; j < 8; ++j) a[j] = (short)f2bf(wv8[j]);
        } else {
            a = *(const bf16x8*)((const unsigned short*)W + woff + kk);
        }
        #pragma unroll
        for (int ns = 0; ns < 4; ++ns) {
            bf16x8 bb = *(const bf16x8*)&Xsh[(ns * 16 + lm) * 40 + qd * 8];
            acc[ns] = __builtin_amdgcn_mfma_f32_16x16x32_bf16(a, bb, acc[ns], 0, 0, 0);
        }
    }

    #pragma unroll
    for (int ns = 0; ns < 4; ++ns) {
        #pragma unroll
        for (int r = 0; r < 4; ++r) {
            int o = m0 + wv * 16 + qd * 4 + r;
            int n = n0 + ns * 16 + lm;
            float vv = acc[ns][r] + loads(bias, o, isf);
            if (resid) vv += loads(resid, ((size_t)b * CH + o) * NTOK + n, isf);
            size_t oidx = (size_t)b * ostride + (size_t)o * NTOK + n;
            if (apply_flag && isf) ((float*)out)[oidx] = vv;
            else ((unsigned short*)out)[oidx] = f2bf(vv);
        }
    }
}

// ------------- MFMA flash attention -------------
// qkv (ws bf16) per batch: rows [0,512) q, [512,1024) k, [1024,1536) v.
// Block: 128 queries (32/wave), loop over 64-key tiles. Output in-place to q region.
// Layouts (HW-verified via the GEMM): A-frag A[m=l15][k=qd*8+j]; B-frag B[k=qd*8+j][n=l15];
// D: row=(qd)*4+r, col=l15.
__global__ __launch_bounds__(256) void attn_kernel(
    const unsigned short* qkv, unsigned short* outq)
{
    __shared__ __align__(16) unsigned short Qsh[128 * 72];  // [n_loc][c], stride 72 (144B)
    __shared__ __align__(16) unsigned short Ksh[64 * 72];   // [m_loc][c]
    __shared__ __align__(16) unsigned short Vsh[64 * 72];   // [c][m_loc]
    __shared__ __align__(16) unsigned short Psh[4][2560];   // per-wave: P [n32][m64] s72; reused as O [c64][n32] s40

    int b = blockIdx.z, h = blockIdx.y;
    int q0 = blockIdx.x * 128;
    int t = threadIdx.x, L = t & 63, wv = t >> 6;
    int l15 = L & 15, qd = L >> 4;

    const unsigned short* qb = qkv + ((size_t)b * 1536 + h * 64) * NTOK;
    const unsigned short* kb = qb + 512 * NTOK;
    const unsigned short* vb = qb + 1024 * NTOK;

    // Stage Q transposed + pre-scaled by 1/sqrt(64)=0.125 (exact in bf16)
    {
        int c = t >> 2, nb = (t & 3) * 32;
        #pragma unroll
        for (int i = 0; i < 4; ++i) {
            u16x8 u = *(const u16x8*)(qb + (size_t)c * NTOK + q0 + nb + i * 8);
            #pragma unroll
            for (int j = 0; j < 8; ++j)
                Qsh[(nb + i * 8 + j) * 72 + c] = f2bf(bf2f(u[j]) * 0.125f);
        }
    }

    f32x4 Oacc[2][4];   // [nt][ct]
    #pragma unroll
    for (int i = 0; i < 2; ++i)
        #pragma unroll
        for (int j = 0; j < 4; ++j) Oacc[i][j] = (f32x4){0.f,0.f,0.f,0.f};
    float mrun[2] = {-1e30f, -1e30f}, lrun[2] = {0.f, 0.f};

    for (int m0 = 0; m0 < NTOK; m0 += 64) {
        __syncthreads();   // prev tile's Ksh/Vsh reads done (covers Qsh on iter 0)
        {
            int c = t >> 2, mb = (t & 3) * 16;
            #pragma unroll
            for (int i = 0; i < 2; ++i) {
                u16x8 ku = *(const u16x8*)(kb + (size_t)c * NTOK + m0 + mb + i * 8);
                #pragma unroll
                for (int j = 0; j < 8; ++j)
                    Ksh[(mb + i * 8 + j) * 72 + c] = ku[j];
                u16x8 vu = *(const u16x8*)(vb + (size_t)c * NTOK + m0 + mb + i * 8);
                *(u16x8*)&Vsh[c * 72 + mb + i * 8] = vu;
            }
        }
        __syncthreads();

        // S^T[m(64)][n(32)] = K^T · Q
        f32x4 st[4][2];
        #pragma unroll
        for (int mt = 0; mt < 4; ++mt)
            #pragma unroll
            for (int nt = 0; nt < 2; ++nt) st[mt][nt] = (f32x4){0.f,0.f,0.f,0.f};
        #pragma unroll
        for (int cc = 0; cc < 2; ++cc) {
            bf16x8 bq[2];
            #pragma unroll
            for (int nt = 0; nt < 2; ++nt)
                bq[nt] = *(const bf16x8*)&Qsh[(wv * 32 + nt * 16 + l15) * 72 + cc * 32 + qd * 8];
            #pragma unroll
            for (int mt = 0; mt < 4; ++mt) {
                bf16x8 a = *(const bf16x8*)&Ksh[(mt * 16 + l15) * 72 + cc * 32 + qd * 8];
                #pragma unroll
                for (int nt = 0; nt < 2; ++nt)
                    st[mt][nt] = __builtin_amdgcn_mfma_f32_16x16x32_bf16(a, bq[nt], st[mt][nt], 0, 0, 0);
            }
        }

        // Online softmax per query col n = nt*16 + l15 (replicated across quads)
        #pragma unroll
        for (int nt = 0; nt < 2; ++nt) {
            float tmax = -1e30f;
            #pragma unroll
            for (int mt = 0; mt < 4; ++mt)
                #pragma unroll
                for (int r = 0; r < 4; ++r) tmax = fmaxf(tmax, st[mt][nt][r]);
            tmax = fmaxf(tmax, __shfl_xor(tmax, 16));
            tmax = fmaxf(tmax, __shfl_xor(tmax, 32));
            float newm = fmaxf(mrun[nt], tmax);
            float alpha = __expf(mrun[nt] - newm);
            mrun[nt] = newm;
            float psum = 0.f;
            #pragma unroll
            for (int mt = 0; mt < 4; ++mt) {
                u16x4 pk;
                #pragma unroll
                for (int r = 0; r < 4; ++r) {
                    float p = __expf(st[mt][nt][r] - newm);
                    psum += p;
                    pk[r] = f2bf(p);
                }
                *(u16x4*)&Psh[wv][(nt * 16 + l15) * 72 + mt * 16 + 4 * qd] = pk;
            }
            psum += __shfl_xor(psum, 16);
            psum += __shfl_xor(psum, 32);
            lrun[nt] = lrun[nt] * alpha + psum;
            // rescale O rows n = nt*16 + 4*qd + r
            #pragma unroll
            for (int r = 0; r < 4; ++r) {
                float ar = __shfl(alpha, 4 * qd + r);
                #pragma unroll
                for (int ct = 0; ct < 4; ++ct) Oacc[nt][ct][r] *= ar;
            }
        }

        // O^T[n][c] += P · V^T
        #pragma unroll
        for (int mk = 0; mk < 2; ++mk) {
            bf16x8 ap[2];
            #pragma unroll
            for (int nt = 0; nt < 2; ++nt)
                ap[nt] = *(const bf16x8*)&Psh[wv][(nt * 16 + l15) * 72 + mk * 32 + qd * 8];
            #pragma unroll
            for (int ct = 0; ct < 4; ++ct) {
                bf16x8 bv = *(const bf16x8*)&Vsh[(ct * 16 + l15) * 72 + mk * 32 + qd * 8];
                #pragma unroll
                for (int nt = 0; nt < 2; ++nt)
                    Oacc[nt][ct] = __builtin_amdgcn_mfma_f32_16x16x32_bf16(ap[nt], bv, Oacc[nt][ct], 0, 0, 0);
            }
        }
    }

    // Epilogue: scale by 1/l, transpose via wave-private LDS (Psh as O[c][n] stride 40)
    #pragma unroll
    for (int nt = 0; nt < 2; ++nt) {
        float inv = 1.f / lrun[nt];
        #pragma unroll
        for (int r = 0; r < 4; ++r) {
            float ir = __shfl(inv, 4 * qd + r);
            #pragma unroll
            for (int ct = 0; ct < 4; ++ct) {
                int c = ct * 16 + l15;
                int n = nt * 16 + 4 * qd + r;
                Psh[wv][c * 40 + n] = f2bf(Oacc[nt][ct][r] * ir);
            }
        }
    }
    // lane L = channel c; write 32 queries (wave's range) coalesced per row
    {
        unsigned short* ob = outq + ((size_t)b * 1536 + h * 64 + L) * NTOK + q0 + wv * 32;
        #pragma unroll
        for (int nc = 0; nc < 4; ++nc) {
            u16x8 o8 = *(const u16x8*)&Psh[wv][L * 40 + nc * 8];
            *(u16x8*)(ob + nc * 8) = o8;
        }
    }
}

extern "C" void kernel_launch(void* const* d_in, const int* in_sizes, int n_in,
                              void* d_out, int out_size, void* d_ws, size_t ws_size,
                              hipStream_t stream) {
    const void* x      = d_in[0];
    const void* norm_w = d_in[1];
    const void* norm_b = d_in[2];
    const void* qkv_w  = d_in[3];
    const void* qkv_b  = d_in[4];
    const void* proj_w = d_in[5];
    const void* proj_b = d_in[6];

    const size_t QKV_BYTES = (size_t)8 * 1536 * 1024 * 2;
    if (ws_size < QKV_BYTES + 8192) return;
    unsigned short* qkvb = (unsigned short*)d_ws;
    float* stats = (float*)((char*)d_ws + QKV_BYTES);
    int* flag = (int*)((char*)d_ws + QKV_BYTES + 4096);

    probe_kernel<<<dim3(1), dim3(256), 0, stream>>>((const unsigned short*)x, flag);
    stats_kernel<<<dim3(256), dim3(256), 0, stream>>>(x, stats, flag);
    gemm_kernel<<<dim3(16, 24, 8), dim3(256), 0, stream>>>(
        qkv_w, qkv_b, x, (long long)CH * NTOK, qkvb, (long long)1536 * NTOK,
        nullptr, 1536, stats, norm_w, norm_b, flag, 0);
    attn_kernel<<<dim3(8, 8, 8), dim3(256), 0, stream>>>(qkvb, qkvb);
    gemm_kernel<<<dim3(16, 8, 8), dim3(256), 0, stream>>>(
        proj_w, proj_b, qkvb, (long long)1536 * NTOK, d_out, (long long)CH * NTOK,
        x, 512, nullptr, nullptr, nullptr, flag, 1);
}